// Round 1
// baseline (160.775 us; speedup 1.0000x reference)
//
#include <hip/hip_runtime.h>
#include <math.h>

#define BB 8
#define HH 256
#define WW 256
#define NPIX (BB*HH*WW)

// ws layout:
//   [0]              double acc          (8 B)
//   [8]              unsigned maxabs[BB] (32 B)
//   [40]             int hasfg[BB]       (32 B)
//   [~80, aligned]   float g2a[NPIX]     (dist_inside^2; phi after edt_row)
//   next             float g2b[NPIX]     (dist_outside^2)

__global__ void init_small(double* acc, unsigned* maxabs, int* hasfg) {
    if (threadIdx.x == 0) *acc = 0.0;
    if (threadIdx.x < BB) { maxabs[threadIdx.x] = 0u; hasfg[threadIdx.x] = 0; }
}

// One thread per (b, w) column. Reproduces reference lax.scan semantics:
// d starts at BIG=512, d = f ? 0 : d+1; g = min(fwd, bwd, 512).
__global__ void colscan(const int* __restrict__ tgt,
                        float* __restrict__ g2a, float* __restrict__ g2b,
                        int* __restrict__ hasfg) {
    int tid = blockIdx.x * blockDim.x + threadIdx.x;
    if (tid >= BB * WW) return;
    int b = tid / WW, w = tid % WW;
    const int* col = tgt + b * HH * WW + w;
    float* ga = g2a + b * HH * WW + w;
    float* gb = g2b + b * HH * WW + w;

    // forward scan (top -> bottom)
    float da = 512.0f, db = 512.0f;  // da: dist to nearest background, db: to foreground
    int any = 0;
    #pragma unroll 4
    for (int i = 0; i < HH; ++i) {
        int fg = (col[i * WW] != 0);
        any |= fg;
        da = fg ? (da + 1.0f) : 0.0f;   // feature = background (~m)
        db = fg ? 0.0f : (db + 1.0f);   // feature = foreground (m)
        ga[i * WW] = da;
        gb[i * WW] = db;
    }
    // backward scan, combine, square
    da = 512.0f; db = 512.0f;
    #pragma unroll 4
    for (int i = HH - 1; i >= 0; --i) {
        int fg = (col[i * WW] != 0);
        da = fg ? (da + 1.0f) : 0.0f;
        db = fg ? 0.0f : (db + 1.0f);
        float a = fminf(fminf(ga[i * WW], da), 512.0f);
        float c = fminf(fminf(gb[i * WW], db), 512.0f);
        ga[i * WW] = a * a;
        gb[i * WW] = c * c;
    }
    if (any) atomicOr(&hasfg[b], 1);
}

// One block per (b, i) row: d2(j) = min_{j'} g2[j'] + (j-j')^2 for both masks.
// phi written in-place over g2a. Per-batch max|phi| via atomicMax on float bits.
__global__ void edt_row(float* __restrict__ g2a, const float* __restrict__ g2b,
                        unsigned* __restrict__ maxabs) {
    __shared__ float sA[WW];
    __shared__ float sB[WW];
    int row = blockIdx.x;          // b*HH + i
    int b = row / HH;
    int j = threadIdx.x;
    const float* ra = g2a + row * WW;
    const float* rb = g2b + row * WW;
    sA[j] = ra[j];
    sB[j] = rb[j];
    __syncthreads();

    float mA = 1e30f, mB = 1e30f;
    #pragma unroll 8
    for (int jp = 0; jp < WW; ++jp) {
        float d = (float)(j - jp);
        float o = d * d;
        mA = fminf(mA, sA[jp] + o);
        mB = fminf(mB, sB[jp] + o);
    }
    float p = sqrtf(mB) - sqrtf(mA);   // dist_outside - dist_inside
    g2a[row * WW + j] = p;             // phi

    // block reduce max |phi|
    float ap = fabsf(p);
    #pragma unroll
    for (int off = 32; off; off >>= 1) ap = fmaxf(ap, __shfl_down(ap, off));
    __shared__ float wmax[4];
    if ((threadIdx.x & 63) == 0) wmax[threadIdx.x >> 6] = ap;
    __syncthreads();
    if (threadIdx.x == 0) {
        float m = fmaxf(fmaxf(wmax[0], wmax[1]), fmaxf(wmax[2], wmax[3]));
        atomicMax(&maxabs[b], __float_as_uint(m));   // |phi| >= 0: bits monotonic
    }
}

__global__ void finalize(const float* __restrict__ phi,
                         const float* __restrict__ pred,
                         const unsigned* __restrict__ maxabs,
                         const int* __restrict__ hasfg,
                         double* __restrict__ acc) {
    int idx0 = blockIdx.x * blockDim.x + threadIdx.x;
    int stride = gridDim.x * blockDim.x;
    double s = 0.0;
    for (int idx = idx0; idx < NPIX; idx += stride) {
        int b = idx / (HH * WW);
        if (hasfg[b]) {
            float denom = __uint_as_float(maxabs[b]) + 1e-8f;
            float p = phi[idx] / denom;
            float x = pred[idx];
            float prob = 1.0f / (1.0f + expf(-x));
            s += (double)(p * prob);
        }
    }
    #pragma unroll
    for (int off = 32; off; off >>= 1) s += __shfl_down(s, off);
    __shared__ double wsum[4];
    if ((threadIdx.x & 63) == 0) wsum[threadIdx.x >> 6] = s;
    __syncthreads();
    if (threadIdx.x == 0) {
        double t = wsum[0] + wsum[1] + wsum[2] + wsum[3];
        atomicAdd(acc, t);
    }
}

__global__ void writeout(const double* __restrict__ acc, float* __restrict__ out) {
    out[0] = (float)(acc[0] / (double)NPIX);
}

extern "C" void kernel_launch(void* const* d_in, const int* in_sizes, int n_in,
                              void* d_out, int out_size, void* d_ws, size_t ws_size,
                              hipStream_t stream) {
    const float* pred = (const float*)d_in[0];
    const int* tgt = (const int*)d_in[1];
    float* out = (float*)d_out;

    char* ws = (char*)d_ws;
    double* acc = (double*)ws;
    unsigned* maxabs = (unsigned*)(ws + 8);
    int* hasfg = (int*)(ws + 8 + BB * sizeof(unsigned));
    float* g2a = (float*)(ws + 128);                 // phi after edt_row
    float* g2b = g2a + NPIX;

    init_small<<<1, 64, 0, stream>>>(acc, maxabs, hasfg);
    colscan<<<(BB * WW + 255) / 256, 256, 0, stream>>>(tgt, g2a, g2b, hasfg);
    edt_row<<<BB * HH, WW, 0, stream>>>(g2a, g2b, maxabs);
    finalize<<<256, 256, 0, stream>>>(g2a, pred, maxabs, hasfg, acc);
    writeout<<<1, 1, 0, stream>>>(acc, out);
}

// Round 2
// 94.065 us; speedup vs baseline: 1.7092x; 1.7092x over previous
//
#include <hip/hip_runtime.h>
#include <math.h>

#define BB 8
#define HH 256
#define WW 256
#define NPIX (BB*HH*WW)

// ws layout:
//   [0]    double bsum[BB]     (64 B)  per-batch sum of phi*prob (undivided)
//   [64]   unsigned maxabs[BB] (32 B)  per-batch max |phi| as float bits
//   [96]   int hasfg[BB]       (32 B)
//   [128]  float2 g2[NPIX]     (4 MB)  (.x = dist_to_bg^2, .y = dist_to_fg^2)

__global__ void init_small(double* bsum, unsigned* maxabs, int* hasfg) {
    int t = threadIdx.x;
    if (t < BB) { bsum[t] = 0.0; maxabs[t] = 0u; hasfg[t] = 0; }
}

// Vertical exact 1D distances via bitmask segments — no serial H-chain.
// 64 blocks x 256 threads. Block = (batch b, 32-column group); thread =
// (segment s of 32 rows, column c). g = min(i - prevFeat, nextFeat - i, 512).
__global__ void colscan(const int* __restrict__ tgt,
                        float2* __restrict__ g2,
                        int* __restrict__ hasfg) {
    __shared__ int hiF[8][32], loF[8][32], hiB[8][32], loB[8][32];
    int tx = threadIdx.x;
    int c = tx & 31, s = tx >> 5;
    int bw = blockIdx.x;              // b*8 + wgroup
    int b = bw >> 3;
    int w = ((bw & 7) << 5) + c;
    const int* col = tgt + b * HH * WW + w;
    int base = s << 5;

    unsigned fgbits = 0;
    #pragma unroll
    for (int r = 0; r < 32; ++r)
        fgbits |= (col[(base + r) * WW] != 0 ? 1u : 0u) << r;
    unsigned bgbits = ~fgbits;

    hiF[s][c] = fgbits ? (base + 31 - __clz(fgbits)) : -1;
    loF[s][c] = fgbits ? (base + __ffs(fgbits) - 1) : -1;
    hiB[s][c] = bgbits ? (base + 31 - __clz(bgbits)) : -1;
    loB[s][c] = bgbits ? (base + __ffs(bgbits) - 1) : -1;
    __syncthreads();

    int prevF = -100000, nextF = 100000, prevB = -100000, nextB = 100000;
    for (int t = 0; t < s; ++t) {
        int h = hiF[t][c]; if (h >= 0) prevF = h;
        int g = hiB[t][c]; if (g >= 0) prevB = g;
    }
    for (int t = 7; t > s; --t) {
        int l = loF[t][c]; if (l >= 0) nextF = l;
        int m = loB[t][c]; if (m >= 0) nextB = m;
    }

    float2* out = g2 + b * HH * WW + w;
    #pragma unroll
    for (int r = 0; r < 32; ++r) {
        int i = base + r;
        unsigned lowmask = 0xFFFFFFFFu >> (31 - r);

        unsigned mf = fgbits & lowmask;
        int pF = mf ? (base + 31 - __clz(mf)) : prevF;
        unsigned nf = fgbits >> r;
        int nF = nf ? (i + __ffs(nf) - 1) : nextF;
        int gFg = min(min(i - pF, nF - i), 512);      // dist to nearest fg

        unsigned mb = bgbits & lowmask;
        int pB = mb ? (base + 31 - __clz(mb)) : prevB;
        unsigned nb = bgbits >> r;
        int nB = nb ? (i + __ffs(nb) - 1) : nextB;
        int gBg = min(min(i - pB, nB - i), 512);      // dist to nearest bg

        float fa = (float)gBg;   // feature = background  -> dist_inside precursor
        float fb = (float)gFg;   // feature = foreground  -> dist_outside precursor
        float2 o; o.x = fa * fa; o.y = fb * fb;
        out[i * WW] = o;
    }

    unsigned long long bal = __ballot(fgbits != 0);
    if ((tx & 63) == 0 && bal) atomicOr(&hasfg[b], 1);
}

// One block per (b,i) row. Each pixel needs only the distance to the
// OPPOSITE class (own-class distance is exactly 0):
//   phi = isBg ? +dist_to_fg : -dist_to_bg.
// Fused epilogue: per-batch Sum(phi*sigmoid(pred)) and max|phi|.
__global__ void edt_fuse(const float2* __restrict__ g2,
                         const float* __restrict__ pred,
                         unsigned* __restrict__ maxabs,
                         double* __restrict__ bsum) {
    __shared__ float s2[WW * 2];
    int row = blockIdx.x;             // b*HH + i
    int b = row >> 8;
    int j = threadIdx.x;

    float2 v = g2[row * WW + j];
    s2[2 * j] = v.x;                  // dist_to_bg^2
    s2[2 * j + 1] = v.y;              // dist_to_fg^2
    bool isBg = (v.x == 0.0f);        // pixel is background iff dist_to_bg == 0
    __syncthreads();

    const float* basep = s2 + (isBg ? 1 : 0);   // bg pixel scans dist_to_fg^2
    float m0 = 1e30f, m1 = 1e30f;
    float d0 = (float)j, d1 = (float)(j - 1);
    #pragma unroll 8
    for (int jp = 0; jp < WW; jp += 2) {
        m0 = fminf(m0, fmaf(d0, d0, basep[2 * jp]));
        m1 = fminf(m1, fmaf(d1, d1, basep[2 * jp + 2]));
        d0 -= 2.0f; d1 -= 2.0f;
    }
    float m = fminf(m0, m1);
    float dist = sqrtf(m);
    float phi = isBg ? dist : -dist;
    float prob = 1.0f / (1.0f + expf(-pred[row * WW + j]));
    double sd = (double)(phi * prob);
    float mx = dist;

    #pragma unroll
    for (int off = 32; off; off >>= 1) {
        mx = fmaxf(mx, __shfl_down(mx, off));
        sd += __shfl_down(sd, off);
    }
    __shared__ float wmax[4];
    __shared__ double wsum[4];
    int wid = j >> 6;
    if ((j & 63) == 0) { wmax[wid] = mx; wsum[wid] = sd; }
    __syncthreads();
    if (j == 0) {
        float mm = fmaxf(fmaxf(wmax[0], wmax[1]), fmaxf(wmax[2], wmax[3]));
        atomicMax(&maxabs[b], __float_as_uint(mm));   // |phi| >= 0: bits monotonic
        atomicAdd(&bsum[b], wsum[0] + wsum[1] + wsum[2] + wsum[3]);
    }
}

__global__ void writeout(const double* __restrict__ bsum,
                         const unsigned* __restrict__ maxabs,
                         const int* __restrict__ hasfg,
                         float* __restrict__ out) {
    if (threadIdx.x == 0) {
        double t = 0.0;
        for (int b = 0; b < BB; ++b) {
            if (hasfg[b]) {
                double denom = (double)__uint_as_float(maxabs[b]) + 1e-8;
                t += bsum[b] / denom;
            }
        }
        out[0] = (float)(t / (double)NPIX);
    }
}

extern "C" void kernel_launch(void* const* d_in, const int* in_sizes, int n_in,
                              void* d_out, int out_size, void* d_ws, size_t ws_size,
                              hipStream_t stream) {
    const float* pred = (const float*)d_in[0];
    const int* tgt = (const int*)d_in[1];
    float* out = (float*)d_out;

    char* ws = (char*)d_ws;
    double* bsum = (double*)ws;
    unsigned* maxabs = (unsigned*)(ws + 64);
    int* hasfg = (int*)(ws + 96);
    float2* g2 = (float2*)(ws + 128);

    init_small<<<1, 64, 0, stream>>>(bsum, maxabs, hasfg);
    colscan<<<64, 256, 0, stream>>>(tgt, g2, hasfg);
    edt_fuse<<<BB * HH, WW, 0, stream>>>(g2, pred, maxabs, bsum);
    writeout<<<1, 64, 0, stream>>>(bsum, maxabs, hasfg, out);
}

// Round 3
// 70.926 us; speedup vs baseline: 2.2668x; 1.3262x over previous
//
#include <hip/hip_runtime.h>
#include <math.h>

#define BB 8
#define HH 256
#define WW 256
#define NPIX (BB*HH*WW)
#define NROWS (BB*HH)   // 2048

// ws layout (byte offsets):
//   [0]      int    hasfg8[64]       per colscan-block fg flag (plain stores)
//   [4096]   float  part_max[2048]   per-row max dist
//   [16384]  double part_sum[2048]   per-row sum(phi*prob)
//   [65536]  float2 g2[NPIX]         (.x = dist_to_bg^2, .y = dist_to_fg^2)
// No init kernel needed: every slot is written before it is read.

// Vertical exact 1D distances via bitmask segments — no serial H-chain.
// 64 blocks x 256 threads. Block = (batch b, 32-column group); thread =
// (segment s of 32 rows, column c). g = min(i - prevFeat, nextFeat - i, 512).
__global__ void colscan(const int* __restrict__ tgt,
                        float2* __restrict__ g2,
                        int* __restrict__ hasfg8) {
    __shared__ int hiF[8][32], loF[8][32], hiB[8][32], loB[8][32];
    __shared__ int wany[4];
    int tx = threadIdx.x;
    int c = tx & 31, s = tx >> 5;
    int bw = blockIdx.x;              // b*8 + wgroup
    int b = bw >> 3;
    int w = ((bw & 7) << 5) + c;
    const int* col = tgt + b * HH * WW + w;
    int base = s << 5;

    unsigned fgbits = 0;
    #pragma unroll
    for (int r = 0; r < 32; ++r)
        fgbits |= (col[(base + r) * WW] != 0 ? 1u : 0u) << r;
    unsigned bgbits = ~fgbits;

    hiF[s][c] = fgbits ? (base + 31 - __clz(fgbits)) : -1;
    loF[s][c] = fgbits ? (base + __ffs(fgbits) - 1) : -1;
    hiB[s][c] = bgbits ? (base + 31 - __clz(bgbits)) : -1;
    loB[s][c] = bgbits ? (base + __ffs(bgbits) - 1) : -1;
    unsigned long long bal = __ballot(fgbits != 0);
    if ((tx & 63) == 0) wany[tx >> 6] = (bal != 0ull);
    __syncthreads();

    int prevF = -100000, nextF = 100000, prevB = -100000, nextB = 100000;
    for (int t = 0; t < s; ++t) {
        int h = hiF[t][c]; if (h >= 0) prevF = h;
        int g = hiB[t][c]; if (g >= 0) prevB = g;
    }
    for (int t = 7; t > s; --t) {
        int l = loF[t][c]; if (l >= 0) nextF = l;
        int m = loB[t][c]; if (m >= 0) nextB = m;
    }

    float2* out = g2 + b * HH * WW + w;
    #pragma unroll
    for (int r = 0; r < 32; ++r) {
        int i = base + r;
        unsigned lowmask = 0xFFFFFFFFu >> (31 - r);

        unsigned mf = fgbits & lowmask;
        int pF = mf ? (base + 31 - __clz(mf)) : prevF;
        unsigned nf = fgbits >> r;
        int nF = nf ? (i + __ffs(nf) - 1) : nextF;
        int gFg = min(min(i - pF, nF - i), 512);      // dist to nearest fg

        unsigned mb = bgbits & lowmask;
        int pB = mb ? (base + 31 - __clz(mb)) : prevB;
        unsigned nb = bgbits >> r;
        int nB = nb ? (i + __ffs(nb) - 1) : nextB;
        int gBg = min(min(i - pB, nB - i), 512);      // dist to nearest bg

        float fa = (float)gBg;
        float fb = (float)gFg;
        float2 o; o.x = fa * fa; o.y = fb * fb;
        out[i * WW] = o;
    }

    if (tx == 0)
        hasfg8[bw] = wany[0] | wany[1] | wany[2] | wany[3];
}

// One block per (b,i) row. phi = isBg ? +dist_to_fg : -dist_to_bg.
// Exact pruned 1D EDT: m starts at own-column opposite g^2 (offset 0 term),
// scan outward k=1,2,..., stop when k^2 >= m (offsets are monotone => exact).
// Fused epilogue: per-row partial sum(phi*prob) and max|phi|, plain stores.
__global__ void edt_fuse(const float2* __restrict__ g2,
                         const float* __restrict__ pred,
                         float* __restrict__ part_max,
                         double* __restrict__ part_sum) {
    __shared__ float sB[3 * WW];   // dist_to_bg^2, idx = 256+jp, +inf pads
    __shared__ float sF[3 * WW];   // dist_to_fg^2
    __shared__ float wmax[4];
    __shared__ double wsum[4];
    int row = blockIdx.x;             // b*HH + i
    int j = threadIdx.x;

    float x = pred[row * WW + j];     // issue early, independent of LDS
    float2 v = g2[row * WW + j];
    sB[j] = 1e30f; sB[2 * WW + j] = 1e30f; sB[WW + j] = v.x;
    sF[j] = 1e30f; sF[2 * WW + j] = 1e30f; sF[WW + j] = v.y;
    bool isBg = (v.x == 0.0f);        // own dist_to_bg == 0 <=> background pixel
    __syncthreads();

    const float* sp = isBg ? sF : sB; // scan distance to the OPPOSITE class
    float m = isBg ? v.y : v.x;       // jp = j term
    int idx = WW + j;
    for (int k = 1; k < WW; ++k) {
        float k2 = (float)(k * k);
        if (k2 >= m) break;           // no farther offset can improve (exact)
        m = fminf(m, sp[idx - k] + k2);
        m = fminf(m, sp[idx + k] + k2);
    }
    float dist = sqrtf(m);
    float phi = isBg ? dist : -dist;
    float prob = 1.0f / (1.0f + expf(-x));
    double sd = (double)(phi * prob);
    float mx = dist;

    #pragma unroll
    for (int off = 32; off; off >>= 1) {
        mx = fmaxf(mx, __shfl_down(mx, off));
        sd += __shfl_down(sd, off);
    }
    int wid = j >> 6;
    if ((j & 63) == 0) { wmax[wid] = mx; wsum[wid] = sd; }
    __syncthreads();
    if (j == 0) {
        part_max[row] = fmaxf(fmaxf(wmax[0], wmax[1]), fmaxf(wmax[2], wmax[3]));
        part_sum[row] = wsum[0] + wsum[1] + wsum[2] + wsum[3];
    }
}

// One block: fold 2048 per-row partials -> scalar.
__global__ void reduce_out(const float* __restrict__ part_max,
                           const double* __restrict__ part_sum,
                           const int* __restrict__ hasfg8,
                           float* __restrict__ out) {
    __shared__ float wmax[4];
    __shared__ double wsum[4];
    int t = threadIdx.x;
    double total = 0.0;
    for (int b = 0; b < BB; ++b) {
        float mx = part_max[b * HH + t];
        double sd = part_sum[b * HH + t];
        #pragma unroll
        for (int off = 32; off; off >>= 1) {
            mx = fmaxf(mx, __shfl_down(mx, off));
            sd += __shfl_down(sd, off);
        }
        if ((t & 63) == 0) { wmax[t >> 6] = mx; wsum[t >> 6] = sd; }
        __syncthreads();
        if (t == 0) {
            int hf = 0;
            #pragma unroll
            for (int q = 0; q < 8; ++q) hf |= hasfg8[b * 8 + q];
            if (hf) {
                float mm = fmaxf(fmaxf(wmax[0], wmax[1]), fmaxf(wmax[2], wmax[3]));
                double dn = (double)mm + 1e-8;
                total += (wsum[0] + wsum[1] + wsum[2] + wsum[3]) / dn;
            }
        }
        __syncthreads();
    }
    if (t == 0) out[0] = (float)(total / (double)NPIX);
}

extern "C" void kernel_launch(void* const* d_in, const int* in_sizes, int n_in,
                              void* d_out, int out_size, void* d_ws, size_t ws_size,
                              hipStream_t stream) {
    const float* pred = (const float*)d_in[0];
    const int* tgt = (const int*)d_in[1];
    float* out = (float*)d_out;

    char* ws = (char*)d_ws;
    int* hasfg8 = (int*)ws;                    // 64 ints
    float* part_max = (float*)(ws + 4096);     // 2048 floats
    double* part_sum = (double*)(ws + 16384);  // 2048 doubles
    float2* g2 = (float2*)(ws + 65536);        // NPIX float2

    colscan<<<64, 256, 0, stream>>>(tgt, g2, hasfg8);
    edt_fuse<<<NROWS, WW, 0, stream>>>(g2, pred, part_max, part_sum);
    reduce_out<<<1, 256, 0, stream>>>(part_max, part_sum, hasfg8, out);
}

// Round 4
// 67.151 us; speedup vs baseline: 2.3942x; 1.0562x over previous
//
#include <hip/hip_runtime.h>
#include <math.h>

#define BB 8
#define HH 256
#define WW 256
#define NPIX (BB*HH*WW)
#define NROWS (BB*HH)   // 2048

// ws layout (byte offsets), everything written before read (no init kernel):
//   [0]      float  part_max[2048]   per-row max dist
//   [8192]   double part_sum[2048]   per-row sum(phi*prob)
//   [24576]  int    part_fg[2048]    per-row "has foreground" flag
//   [65536]  float2 g2[NPIX]         (.x = dist_to_bg^2, .y = dist_to_fg^2)

// Vertical exact 1D distances. 128 blocks x 512 threads.
// Block = (batch b, 16-col group, line-aligned); thread = (col c=tx>>5,
// 8-row segment s=tx&31). Carries across the 32 segments of a column are
// register shuffle scans (lanes 0..31 / 32..63 of a wave are one column).
// g = min(up, down, 512); store g^2 for both classes.
__global__ void colscan(const int* __restrict__ tgt,
                        float2* __restrict__ g2) {
    int tx = threadIdx.x;
    int s = tx & 31, c = tx >> 5;
    int bw = blockIdx.x;              // b*16 + colgroup
    int b = bw >> 4;
    int w = ((bw & 15) << 4) + c;
    const int* col = tgt + b * (HH * WW) + w;
    int base = s << 3;                // rows [base, base+8)

    unsigned fgbits = 0;
    #pragma unroll
    for (int r = 0; r < 8; ++r)
        fgbits |= (col[(base + r) * WW] != 0 ? 1u : 0u) << r;
    unsigned bgbits = (~fgbits) & 0xFFu;

    const int BIGI = 1 << 20;
    // in-segment summaries (absolute row indices)
    int hiF = fgbits ? base + (31 - __clz(fgbits)) : -1;
    int hiB = bgbits ? base + (31 - __clz(bgbits)) : -1;
    int loF = fgbits ? base + (__ffs(fgbits) - 1) : BIGI;
    int loB = bgbits ? base + (__ffs(bgbits) - 1) : BIGI;

    // exclusive prefix-max over segments (last feature row above my segment)
    int aF = hiF, aB = hiB;
    #pragma unroll
    for (int d = 1; d < 32; d <<= 1) {
        int vF = __shfl_up(aF, d, 32);
        int vB = __shfl_up(aB, d, 32);
        if (s >= d) { aF = max(aF, vF); aB = max(aB, vB); }
    }
    int pF = __shfl_up(aF, 1, 32);
    int pB = __shfl_up(aB, 1, 32);
    if (s == 0) { pF = -1; pB = -1; }
    if (pF < 0) pF = -BIGI;
    if (pB < 0) pB = -BIGI;

    // exclusive suffix-min (first feature row below my segment)
    int cF = loF, cB = loB;
    #pragma unroll
    for (int d = 1; d < 32; d <<= 1) {
        int vF = __shfl_down(cF, d, 32);
        int vB = __shfl_down(cB, d, 32);
        if (s < 32 - d) { cF = min(cF, vF); cB = min(cB, vB); }
    }
    int nF = __shfl_down(cF, 1, 32);
    int nB = __shfl_down(cB, 1, 32);
    if (s == 31) { nF = BIGI; nB = BIGI; }

    // downward distances, reverse recurrence: dD(i) = f(i)?0:dD(i+1)+1
    int dDF[8], dDB[8];
    int dF = nF - (base + 8);
    int dB = nB - (base + 8);
    #pragma unroll
    for (int r = 7; r >= 0; --r) {
        dF = ((fgbits >> r) & 1) ? 0 : dF + 1;
        dB = ((bgbits >> r) & 1) ? 0 : dB + 1;
        dDF[r] = dF; dDB[r] = dB;
    }

    // upward distances forward + combine + store
    float2* out = g2 + b * (HH * WW) + w;
    int uF = (base - 1) - pF;
    int uB = (base - 1) - pB;
    #pragma unroll
    for (int r = 0; r < 8; ++r) {
        uF = ((fgbits >> r) & 1) ? 0 : uF + 1;
        uB = ((bgbits >> r) & 1) ? 0 : uB + 1;
        int gF = min(min(uF, dDF[r]), 512);   // dist to nearest fg
        int gB = min(min(uB, dDB[r]), 512);   // dist to nearest bg
        float fB = (float)gB, fF = (float)gF;
        float2 o; o.x = fB * fB; o.y = fF * fF;
        out[(base + r) * WW] = o;
    }
}

// One block per (b,i) row. phi = isBg ? +dist_to_fg : -dist_to_bg
// (own-class distance is exactly 0). Pruned exact 1D EDT: start at own
// column's opposite g^2, scan outward, stop when k^2 >= m (offsets
// monotone => exact). Fused: per-row sum(phi*prob), max|phi|, fg flag.
__global__ void edt_fuse(const float2* __restrict__ g2,
                         const float* __restrict__ pred,
                         float* __restrict__ part_max,
                         double* __restrict__ part_sum,
                         int* __restrict__ part_fg) {
    __shared__ float sB[3 * WW];   // dist_to_bg^2 at idx WW+jp, +inf pads
    __shared__ float sF[3 * WW];   // dist_to_fg^2
    __shared__ float wmax[4];
    __shared__ double wsum[4];
    __shared__ int wfg[4];
    int row = blockIdx.x;             // b*HH + i
    int j = threadIdx.x;

    float x = pred[row * WW + j];     // independent of LDS, issue early
    float2 v = g2[row * WW + j];
    sB[j] = 1e30f; sB[2 * WW + j] = 1e30f; sB[WW + j] = v.x;
    sF[j] = 1e30f; sF[2 * WW + j] = 1e30f; sF[WW + j] = v.y;
    bool isBg = (v.x == 0.0f);        // own dist_to_bg == 0 <=> background
    unsigned long long fgb = __ballot(v.y == 0.0f);   // lane is fg pixel
    __syncthreads();

    const float* sp = isBg ? sF : sB; // scan the OPPOSITE class
    float m = isBg ? v.y : v.x;       // jp = j term
    int idx = WW + j;
    for (int k = 1; k < WW; ++k) {
        float k2 = (float)(k * k);
        if (k2 >= m) break;           // exact termination
        m = fminf(m, sp[idx - k] + k2);
        m = fminf(m, sp[idx + k] + k2);
    }
    float dist = sqrtf(m);
    float phi = isBg ? dist : -dist;
    float prob = 1.0f / (1.0f + expf(-x));
    double sd = (double)(phi * prob);
    float mx = dist;

    #pragma unroll
    for (int off = 32; off; off >>= 1) {
        mx = fmaxf(mx, __shfl_down(mx, off));
        sd += __shfl_down(sd, off);
    }
    int wid = j >> 6;
    if ((j & 63) == 0) { wmax[wid] = mx; wsum[wid] = sd; wfg[wid] = (fgb != 0ull); }
    __syncthreads();
    if (j == 0) {
        part_max[row] = fmaxf(fmaxf(wmax[0], wmax[1]), fmaxf(wmax[2], wmax[3]));
        part_sum[row] = wsum[0] + wsum[1] + wsum[2] + wsum[3];
        part_fg[row] = wfg[0] | wfg[1] | wfg[2] | wfg[3];
    }
}

// One block, 4 waves; wave w folds batches 2w and 2w+1 (256 rows each).
__global__ void reduce_out(const float* __restrict__ part_max,
                           const double* __restrict__ part_sum,
                           const int* __restrict__ part_fg,
                           float* __restrict__ out) {
    __shared__ double terms[8];
    int tx = threadIdx.x;
    int wv = tx >> 6, l = tx & 63;
    #pragma unroll
    for (int q = 0; q < 2; ++q) {
        int b = wv * 2 + q;
        int base = b * HH;
        float mx = fmaxf(fmaxf(part_max[base + l], part_max[base + l + 64]),
                         fmaxf(part_max[base + l + 128], part_max[base + l + 192]));
        double sd = part_sum[base + l] + part_sum[base + l + 64]
                  + part_sum[base + l + 128] + part_sum[base + l + 192];
        int fg = part_fg[base + l] | part_fg[base + l + 64]
               | part_fg[base + l + 128] | part_fg[base + l + 192];
        #pragma unroll
        for (int off = 32; off; off >>= 1) {
            mx = fmaxf(mx, __shfl_down(mx, off));
            sd += __shfl_down(sd, off);
            fg |= __shfl_down(fg, off);
        }
        if (l == 0) terms[b] = fg ? sd / ((double)mx + 1e-8) : 0.0;
    }
    __syncthreads();
    if (tx == 0) {
        double t = 0.0;
        #pragma unroll
        for (int b = 0; b < BB; ++b) t += terms[b];
        out[0] = (float)(t / (double)NPIX);
    }
}

extern "C" void kernel_launch(void* const* d_in, const int* in_sizes, int n_in,
                              void* d_out, int out_size, void* d_ws, size_t ws_size,
                              hipStream_t stream) {
    const float* pred = (const float*)d_in[0];
    const int* tgt = (const int*)d_in[1];
    float* out = (float*)d_out;

    char* ws = (char*)d_ws;
    float* part_max = (float*)ws;              // 2048 floats
    double* part_sum = (double*)(ws + 8192);   // 2048 doubles
    int* part_fg = (int*)(ws + 24576);         // 2048 ints
    float2* g2 = (float2*)(ws + 65536);        // NPIX float2

    colscan<<<128, 512, 0, stream>>>(tgt, g2);
    edt_fuse<<<NROWS, WW, 0, stream>>>(g2, pred, part_max, part_sum, part_fg);
    reduce_out<<<1, 256, 0, stream>>>(part_max, part_sum, part_fg, out);
}